// Round 4
// baseline (219.211 us; speedup 1.0000x reference)
//
#include <hip/hip_runtime.h>
#include <math.h>

#define BB 4
#define CDIM 256
#define NN 2048
#define HEADS 8
#define DH 64
#define HIDDEN 512
#define THREEH 1536
#define QSCALE 0.18033688011112042f   // 0.125 * log2(e): softmax in exp2 domain

typedef __attribute__((ext_vector_type(8))) short bf16x8;
typedef __attribute__((ext_vector_type(4))) float f32x4;

static __device__ inline unsigned short f2bf(float f) {
    unsigned u = __float_as_uint(f);
    u += 0x7fff + ((u >> 16) & 1);
    return (unsigned short)(u >> 16);
}
#if __has_builtin(__builtin_amdgcn_cvt_pk_bf16_f32)
static __device__ inline unsigned pk2(float a, float b) {
    auto v = __builtin_amdgcn_cvt_pk_bf16_f32(a, b);
    return __builtin_bit_cast(unsigned, v);
}
#else
static __device__ inline unsigned pk2(float a, float b) {
    return (unsigned)f2bf(a) | ((unsigned)f2bf(b) << 16);
}
#endif
#if __has_builtin(__builtin_amdgcn_exp2f)
#define EXP2(x) __builtin_amdgcn_exp2f(x)
#else
#define EXP2(x) exp2f(x)
#endif
#define MFMA16(a, b, c) __builtin_amdgcn_mfma_f32_16x16x32_bf16(a, b, c, 0, 0, 0)
// XOR swizzle: 8-elem chunks within a tight 64-elem row; key = row&7. <=2-way banks on b128.
#define SWZ(row, chunk) ((((chunk) ^ ((row) & 7)) << 3))

// ---------------- prep_w: fp32 weights -> bf16 (Q rows pre-scaled by QSCALE) ----------------
__global__ __launch_bounds__(256) void prep_w(const float* __restrict__ wqkv,
                                              const float* __restrict__ wout,
                                              unsigned* __restrict__ Wqb,
                                              unsigned* __restrict__ Wob) {
    const int t = blockIdx.x * 256 + threadIdx.x;
    if (t < 98304) {
        const int e = t * 4;
        const int o = e >> 8;
        const float s = (o < HIDDEN) ? QSCALE : 1.f;
        float4 v = *(const float4*)&wqkv[e];
        Wqb[t * 2 + 0] = pk2(v.x * s, v.y * s);
        Wqb[t * 2 + 1] = pk2(v.z * s, v.w * s);
    } else {
        const int e = (t - 98304) * 4;
        float4 v = *(const float4*)&wout[e];
        Wob[(t - 98304) * 2 + 0] = pk2(v.x, v.y);
        Wob[(t - 98304) * 2 + 1] = pk2(v.z, v.w);
    }
}

// ---------------- prep_x: x[b][c][n] fp32 -> Xt[b][n][c] bf16 (one-time transpose) ----------------
__global__ __launch_bounds__(256) void prep_x(const float* __restrict__ x,
                                              unsigned short* __restrict__ Xt) {
    __shared__ float Ls[64][65];
    const int n0 = blockIdx.x * 64, c0 = blockIdx.y * 64, b = blockIdx.z;
    const int t = threadIdx.x;
    const int r16 = t >> 4, c16 = t & 15;
#pragma unroll
    for (int s = 0; s < 4; ++s) {   // coalesced over n
        const int c = s * 16 + r16;
        float4 v = *(const float4*)&x[((size_t)(b * CDIM + c0 + c)) * NN + n0 + c16 * 4];
        *(float4*)&Ls[c][c16 * 4] = v;
    }
    __syncthreads();
#pragma unroll
    for (int s = 0; s < 4; ++s) {   // coalesced over c
        const int n = s * 16 + r16;
        const int c4 = c16 * 4;
        uint2 u;
        u.x = pk2(Ls[c4][n], Ls[c4 + 1][n]);
        u.y = pk2(Ls[c4 + 2][n], Ls[c4 + 3][n]);
        *(uint2*)&Xt[((size_t)(b * NN) + n0 + n) * CDIM + c0 + c4] = u;
    }
}

// ---------------- Kernel A: qkv projection, LDS-free register GEMM ----------------
// Q/K (o0<1024): D[o][n], A=Wqb rows o, B=Xt rows n -> store [bh][n][c]
// V   (o0>=1024): D[n][o], A=Xt rows n, B=Wqb rows o -> store [bh][c][m]
__global__ __launch_bounds__(256, 4) void qkv_gemm(const unsigned short* __restrict__ Xt,
                                                   const unsigned short* __restrict__ Wqb,
                                                   unsigned short* __restrict__ Qb,
                                                   unsigned short* __restrict__ Kb,
                                                   unsigned short* __restrict__ Vb) {
    const int n0 = blockIdx.x * 64, o0 = blockIdx.y * 64, b = blockIdx.z;
    const int t = threadIdx.x, l = t & 63, w4 = t >> 6, lo = l & 15, quad = l >> 4;
    const unsigned short* xb = Xt + (size_t)(b * NN) * CDIM;
    f32x4 acc[4];
#pragma unroll
    for (int i = 0; i < 4; ++i) acc[i] = (f32x4){0.f, 0.f, 0.f, 0.f};
    if (o0 < 2 * HIDDEN) {
        const unsigned short* arow = Wqb + (size_t)(o0 + 16 * w4 + lo) * CDIM;
#pragma unroll
        for (int kc = 0; kc < CDIM; kc += 32) {
            bf16x8 a = *(const bf16x8*)&arow[kc + quad * 8];
#pragma unroll
            for (int nt = 0; nt < 4; ++nt) {
                bf16x8 bx = *(const bf16x8*)&xb[(size_t)(n0 + nt * 16 + lo) * CDIM + kc + quad * 8];
                acc[nt] = MFMA16(a, bx, acc[nt]);
            }
        }
        const bool isK = (o0 >= HIDDEN);
        const int h = (isK ? (o0 - HIDDEN) : o0) >> 6;
        unsigned short* dst = isK ? Kb : Qb;
        const int c0 = 16 * w4 + quad * 4;   // D rows o -> c (quad*4+reg)
#pragma unroll
        for (int nt = 0; nt < 4; ++nt) {
            const int n = n0 + nt * 16 + lo;
            uint2 u;
            u.x = pk2(acc[nt][0], acc[nt][1]);
            u.y = pk2(acc[nt][2], acc[nt][3]);
            *(uint2*)&dst[(((size_t)(b * HEADS + h)) * NN + n) * DH + c0] = u;
        }
    } else {
        const unsigned short* arow = xb + (size_t)(n0 + 16 * w4 + lo) * CDIM;
#pragma unroll
        for (int kc = 0; kc < CDIM; kc += 32) {
            bf16x8 a = *(const bf16x8*)&arow[kc + quad * 8];
#pragma unroll
            for (int ot = 0; ot < 4; ++ot) {
                bf16x8 bw = *(const bf16x8*)&Wqb[(size_t)(o0 + ot * 16 + lo) * CDIM + kc + quad * 8];
                acc[ot] = MFMA16(a, bw, acc[ot]);
            }
        }
        const int h = (o0 - 2 * HIDDEN) >> 6;
        const int mb = n0 + 16 * w4 + quad * 4;   // D rows n -> m
#pragma unroll
        for (int ot = 0; ot < 4; ++ot) {
            const int c = ot * 16 + lo;
            uint2 u;
            u.x = pk2(acc[ot][0], acc[ot][1]);
            u.y = pk2(acc[ot][2], acc[ot][3]);
            *(uint2*)&Vb[(((size_t)(b * HEADS + h)) * DH + c) * NN + mb] = u;
        }
    }
}

// ---------------- Kernel B: MFMA flash attention (S^T form, swizzled LDS) ----------------
__global__ __launch_bounds__(256, 6) void flash_attn(const unsigned short* __restrict__ Qb,
                                                     const unsigned short* __restrict__ Kb,
                                                     const unsigned short* __restrict__ Vb,
                                                     unsigned short* __restrict__ Yb) {
    __shared__ unsigned short Ks[64 * 64], Vs[64 * 64], Ps[64 * 64];
    // XCD-swizzled 1D grid: all 32 q-tiles of one (b,h) land on one XCD (flat%8 == bh&7)
    const int flat = blockIdx.x;
    const int rest = flat >> 3;
    const int bh = ((rest & 3) << 3) | (flat & 7);
    const int q0 = (rest >> 2) * 64;
    const int b = bh >> 3, h = bh & 7;
    const int t = threadIdx.x, l = t & 63, w = t >> 6, lo = l & 15, quad = l >> 4;
    const unsigned short* Qp = Qb + (size_t)bh * NN * DH;
    const unsigned short* Kp = Kb + (size_t)bh * NN * DH;
    const unsigned short* Vp = Vb + (size_t)bh * DH * NN;
    const int q = q0 + 16 * w + lo;
    const bf16x8 bQ0 = *(const bf16x8*)&Qp[(size_t)q * DH + quad * 8];
    const bf16x8 bQ1 = *(const bf16x8*)&Qp[(size_t)q * DH + 32 + quad * 8];
    f32x4 O[4];
#pragma unroll
    for (int i = 0; i < 4; ++i) O[i] = (f32x4){0.f, 0.f, 0.f, 0.f};
    float m_i = -INFINITY, l_i = 0.f;
    const int sr = t >> 3, sc = t & 7;           // staging: rows sr, sr+32; 16B chunk sc
    const int kst0 = sr * 64 + SWZ(sr, sc);      // swizzled LDS dests (key sr&7 == (sr+32)&7)
    const int key = lo & 7;

    for (int m0 = 0; m0 < NN; m0 += 64) {
        __syncthreads();
        *(uint4*)&Ks[kst0]            = *(const uint4*)&Kp[(size_t)(m0 + sr) * DH + sc * 8];
        *(uint4*)&Ks[kst0 + 32 * 64]  = *(const uint4*)&Kp[(size_t)(m0 + sr + 32) * DH + sc * 8];
        *(uint4*)&Vs[kst0]            = *(const uint4*)&Vp[(size_t)sr * NN + m0 + sc * 8];
        *(uint4*)&Vs[kst0 + 32 * 64]  = *(const uint4*)&Vp[(size_t)(sr + 32) * NN + m0 + sc * 8];
        __syncthreads();
        // ---- S^T = K·Q^T : rows m = nt*16+quad*4+r, col q = 16w+lo ----
        f32x4 S[4];
#pragma unroll
        for (int nt = 0; nt < 4; ++nt) {
            const int rb = (nt * 16 + lo) * 64;
            bf16x8 a0 = *(const bf16x8*)&Ks[rb + SWZ(lo, quad)];
            bf16x8 a1 = *(const bf16x8*)&Ks[rb + SWZ(lo, quad + 4)];
            f32x4 z = (f32x4){0.f, 0.f, 0.f, 0.f};
            z = MFMA16(a0, bQ0, z);
            z = MFMA16(a1, bQ1, z);
            S[nt] = z;
        }
        // ---- online softmax (per-thread scalar state; cross-quad via 2 shuffles) ----
        float mx;
        {
            f32x4 mm;
#pragma unroll
            for (int i = 0; i < 4; ++i)
                mm[i] = fmaxf(fmaxf(S[0][i], S[1][i]), fmaxf(S[2][i], S[3][i]));
            mx = fmaxf(fmaxf(mm[0], mm[1]), fmaxf(mm[2], mm[3]));
        }
        mx = fmaxf(mx, __shfl_xor(mx, 16));
        mx = fmaxf(mx, __shfl_xor(mx, 32));
        const float mn = fmaxf(m_i, mx);
        const float alpha = EXP2(m_i - mn);
        m_i = mn;
        float ls = 0.f;
        const int prow = (16 * w + lo) * 64;
#pragma unroll
        for (int nt = 0; nt < 4; ++nt) {   // exp2, row-sum, pack, wave-private LDS write
            f32x4 p;
#pragma unroll
            for (int i = 0; i < 4; ++i) p[i] = EXP2(S[nt][i] - mn);
            ls += (p[0] + p[1]) + (p[2] + p[3]);
            uint2 u;
            u.x = pk2(p[0], p[1]);
            u.y = pk2(p[2], p[3]);
            *(uint2*)&Ps[prow + (((nt * 2 + (quad >> 1)) ^ key) << 3) + (quad & 1) * 4] = u;
        }
        ls += __shfl_xor(ls, 16);
        ls += __shfl_xor(ls, 32);
        l_i = l_i * alpha + ls;
        asm volatile("s_waitcnt lgkmcnt(0)" ::: "memory");   // same-wave P write->read drain
#pragma unroll
        for (int ct = 0; ct < 4; ++ct) O[ct] *= alpha;
        const bf16x8 pb0 = *(const bf16x8*)&Ps[prow + SWZ(lo, quad)];
        const bf16x8 pb1 = *(const bf16x8*)&Ps[prow + SWZ(lo, quad + 4)];
        // ---- O^T += V^T·P^T ----
#pragma unroll
        for (int ct = 0; ct < 4; ++ct) {
            const int rb = (ct * 16 + lo) * 64;
            bf16x8 a0 = *(const bf16x8*)&Vs[rb + SWZ(lo, quad)];
            bf16x8 a1 = *(const bf16x8*)&Vs[rb + SWZ(lo, quad + 4)];
            O[ct] = MFMA16(a0, pb0, O[ct]);
            O[ct] = MFMA16(a1, pb1, O[ct]);
        }
    }
    const float inv = 1.f / l_i;
    unsigned short* yrow = Yb + (((size_t)(b * NN) + q)) * HIDDEN + h * DH;
#pragma unroll
    for (int ct = 0; ct < 4; ++ct) {
        uint2 u;
        u.x = pk2(O[ct][0] * inv, O[ct][1] * inv);
        u.y = pk2(O[ct][2] * inv, O[ct][3] * inv);
        *(uint2*)&yrow[ct * 16 + quad * 4] = u;
    }
}

// ---------------- Kernel C: out projection, LDS-free register GEMM + bias ----------------
__global__ __launch_bounds__(256, 4) void out_gemm(const unsigned short* __restrict__ Yb,
                                                   const unsigned short* __restrict__ Wob,
                                                   const float* __restrict__ bias,
                                                   float* __restrict__ out) {
    const int n0 = blockIdx.x * 64, o0 = blockIdx.y * 64, b = blockIdx.z;
    const int t = threadIdx.x, l = t & 63, w4 = t >> 6, lo = l & 15, quad = l >> 4;
    f32x4 acc[4];
#pragma unroll
    for (int i = 0; i < 4; ++i) acc[i] = (f32x4){0.f, 0.f, 0.f, 0.f};
    const unsigned short* ya = Yb + ((size_t)(b * NN) + n0 + 16 * w4 + lo) * HIDDEN;
#pragma unroll 4
    for (int kc = 0; kc < HIDDEN; kc += 32) {
        bf16x8 a = *(const bf16x8*)&ya[kc + quad * 8];
#pragma unroll
        for (int ot = 0; ot < 4; ++ot) {
            bf16x8 bw = *(const bf16x8*)&Wob[(size_t)(o0 + ot * 16 + lo) * HIDDEN + kc + quad * 8];
            acc[ot] = MFMA16(a, bw, acc[ot]);
        }
    }
#pragma unroll
    for (int ot = 0; ot < 4; ++ot) {
        const int o = o0 + ot * 16 + lo;
        const float bv = bias[o];
        *(f32x4*)&out[((size_t)(b * CDIM) + o) * NN + n0 + 16 * w4 + quad * 4] = acc[ot] + bv;
    }
}

extern "C" void kernel_launch(void* const* d_in, const int* in_sizes, int n_in,
                              void* d_out, int out_size, void* d_ws, size_t ws_size,
                              hipStream_t stream) {
    const float* x     = (const float*)d_in[0];
    const float* w_qkv = (const float*)d_in[1];
    const float* w_out = (const float*)d_in[2];
    const float* b_out = (const float*)d_in[3];
    float* out = (float*)d_out;

    unsigned short* Wqb = (unsigned short*)d_ws;                  // 1536*256
    unsigned short* Wob = Wqb + (size_t)THREEH * CDIM;            // 256*512
    unsigned short* Xt  = Wob + (size_t)CDIM * HIDDEN;            // [b][n][c] bf16
    unsigned short* Qb  = Xt + (size_t)BB * NN * CDIM;            // [b][h][n][c] pre-scaled
    unsigned short* Kb  = Qb + (size_t)BB * HEADS * NN * DH;      // [b][h][n][c]
    unsigned short* Vb  = Kb + (size_t)BB * HEADS * NN * DH;      // [b][h][c][n]
    unsigned short* Yb  = Vb + (size_t)BB * HEADS * DH * NN;      // [b][n][hidden]

    prep_w<<<512, 256, 0, stream>>>(w_qkv, w_out, (unsigned*)Wqb, (unsigned*)Wob);
    prep_x<<<dim3(NN / 64, CDIM / 64, BB), 256, 0, stream>>>(x, Xt);
    qkv_gemm<<<dim3(NN / 64, THREEH / 64, BB), 256, 0, stream>>>(Xt, Wqb, Qb, Kb, Vb);
    flash_attn<<<1024, 256, 0, stream>>>(Qb, Kb, Vb, Yb);
    out_gemm<<<dim3(NN / 64, CDIM / 64, BB), 256, 0, stream>>>(Yb, Wob, b_out, out);
}

// Round 5
// 164.721 us; speedup vs baseline: 1.3308x; 1.3308x over previous
//
#include <hip/hip_runtime.h>
#include <math.h>

#define BB 4
#define CDIM 256
#define NN 2048
#define HEADS 8
#define DH 64
#define HIDDEN 512
#define THREEH 1536
#define QSCALE 0.18033688011112042f   // 0.125 * log2(e): softmax in exp2 domain

typedef __attribute__((ext_vector_type(8))) short bf16x8;
typedef __attribute__((ext_vector_type(4))) float f32x4;

static __device__ inline unsigned short f2bf(float f) {
    unsigned u = __float_as_uint(f);
    u += 0x7fff + ((u >> 16) & 1);
    return (unsigned short)(u >> 16);
}
#if __has_builtin(__builtin_amdgcn_cvt_pk_bf16_f32)
static __device__ inline unsigned pk2(float a, float b) {
    auto v = __builtin_amdgcn_cvt_pk_bf16_f32(a, b);
    return __builtin_bit_cast(unsigned, v);
}
#else
static __device__ inline unsigned pk2(float a, float b) {
    return (unsigned)f2bf(a) | ((unsigned)f2bf(b) << 16);
}
#endif
#if __has_builtin(__builtin_amdgcn_exp2f)
#define EXP2(x) __builtin_amdgcn_exp2f(x)
#else
#define EXP2(x) exp2f(x)
#endif
#define MFMA16(a, b, c) __builtin_amdgcn_mfma_f32_16x16x32_bf16(a, b, c, 0, 0, 0)
// XOR swizzle on tight 64-elem (128B) rows, 16B chunks, key=row&7: <=2-way banks on b128 frags.
#define SWZC(row, ch) ((((ch) ^ ((row) & 7)) << 3))

// ---------------- prep_w: fp32 weights -> bf16 (Q rows pre-scaled by QSCALE) ----------------
__global__ __launch_bounds__(256) void prep_w(const float* __restrict__ wqkv,
                                              const float* __restrict__ wout,
                                              unsigned* __restrict__ Wqb,
                                              unsigned* __restrict__ Wob) {
    const int t = blockIdx.x * 256 + threadIdx.x;
    if (t < 98304) {
        const int e = t * 4;
        const int o = e >> 8;
        const float s = (o < HIDDEN) ? QSCALE : 1.f;
        float4 v = *(const float4*)&wqkv[e];
        Wqb[t * 2 + 0] = pk2(v.x * s, v.y * s);
        Wqb[t * 2 + 1] = pk2(v.z * s, v.w * s);
    } else {
        const int e = (t - 98304) * 4;
        float4 v = *(const float4*)&wout[e];
        Wob[(t - 98304) * 2 + 0] = pk2(v.x, v.y);
        Wob[(t - 98304) * 2 + 1] = pk2(v.z, v.w);
    }
}

// ---------------- prep_x: x[b][c][n] fp32 -> Xt[b][n][c] bf16 (one-time transpose) ----------------
__global__ __launch_bounds__(256) void prep_x(const float* __restrict__ x,
                                              unsigned short* __restrict__ Xt) {
    __shared__ float Ls[64][65];
    const int n0 = blockIdx.x * 64, c0 = blockIdx.y * 64, b = blockIdx.z;
    const int t = threadIdx.x;
    const int r16 = t >> 4, c16 = t & 15;
#pragma unroll
    for (int s = 0; s < 4; ++s) {
        const int c = s * 16 + r16;
        float4 v = *(const float4*)&x[((size_t)(b * CDIM + c0 + c)) * NN + n0 + c16 * 4];
        *(float4*)&Ls[c][c16 * 4] = v;
    }
    __syncthreads();
#pragma unroll
    for (int s = 0; s < 4; ++s) {
        const int n = s * 16 + r16;
        const int c4 = c16 * 4;
        uint2 u;
        u.x = pk2(Ls[c4][n], Ls[c4 + 1][n]);
        u.y = pk2(Ls[c4 + 2][n], Ls[c4 + 3][n]);
        *(uint2*)&Xt[((size_t)(b * NN) + n0 + n) * CDIM + c0 + c4] = u;
    }
}

// ---------------- Kernel A: qkv projection, 128x128 LDS-tiled MFMA GEMM ----------------
// A-matrix Xt rows bn (8192 x 256), B-matrix Wqb rows o (1536 x 256).
// Q/K o-tiles: D[o][n] (A=W) -> rows o give 4 consecutive c -> [bh][n][c] uint2 stores.
// V   o-tiles: D[n][o] (A=Xt) -> rows n give 4 consecutive m -> [bh][c][m] uint2 stores.
__global__ __launch_bounds__(256, 3) void qkv_gemm(const unsigned short* __restrict__ Xt,
                                                   const unsigned short* __restrict__ Wqb,
                                                   unsigned short* __restrict__ Qb,
                                                   unsigned short* __restrict__ Kb,
                                                   unsigned short* __restrict__ Vb) {
    __shared__ unsigned short Xs[128 * 64], Ws[128 * 64];
    const int bn0 = blockIdx.x * 128, o0 = blockIdx.y * 128;
    const int t = threadIdx.x, l = t & 63, w = t >> 6, lo = l & 15, quad = l >> 4;
    const int wo = (w >> 1) * 64, wn = (w & 1) * 64;     // wave quadrant: o-half, n-half
    const int sr = t >> 1, scb = (t & 1) * 4;            // staging: row, 4-chunk base
    const bool isV = (o0 >= 2 * HIDDEN);
    f32x4 acc[4][4];
#pragma unroll
    for (int i = 0; i < 4; ++i)
#pragma unroll
        for (int j = 0; j < 4; ++j) acc[i][j] = (f32x4){0.f, 0.f, 0.f, 0.f};

    for (int kc = 0; kc < CDIM; kc += 64) {
        __syncthreads();
#pragma unroll
        for (int j = 0; j < 4; ++j) {
            const int ch = scb + j;
            *(uint4*)&Xs[sr * 64 + SWZC(sr, ch)] =
                *(const uint4*)&Xt[(size_t)(bn0 + sr) * CDIM + kc + ch * 8];
            *(uint4*)&Ws[sr * 64 + SWZC(sr, ch)] =
                *(const uint4*)&Wqb[(size_t)(o0 + sr) * CDIM + kc + ch * 8];
        }
        __syncthreads();
#pragma unroll
        for (int kk = 0; kk < 2; ++kk) {
            const int swz = SWZC(lo, kk * 4 + quad);
            if (!isV) {
                bf16x8 af[4], bv[4];
#pragma unroll
                for (int ot = 0; ot < 4; ++ot) af[ot] = *(const bf16x8*)&Ws[(wo + ot * 16 + lo) * 64 + swz];
#pragma unroll
                for (int nt = 0; nt < 4; ++nt) bv[nt] = *(const bf16x8*)&Xs[(wn + nt * 16 + lo) * 64 + swz];
#pragma unroll
                for (int ot = 0; ot < 4; ++ot)
#pragma unroll
                    for (int nt = 0; nt < 4; ++nt) acc[ot][nt] = MFMA16(af[ot], bv[nt], acc[ot][nt]);
            } else {
                bf16x8 af[4], bv[4];
#pragma unroll
                for (int mt = 0; mt < 4; ++mt) af[mt] = *(const bf16x8*)&Xs[(wn + mt * 16 + lo) * 64 + swz];
#pragma unroll
                for (int ot = 0; ot < 4; ++ot) bv[ot] = *(const bf16x8*)&Ws[(wo + ot * 16 + lo) * 64 + swz];
#pragma unroll
                for (int mt = 0; mt < 4; ++mt)
#pragma unroll
                    for (int ot = 0; ot < 4; ++ot) acc[mt][ot] = MFMA16(af[mt], bv[ot], acc[mt][ot]);
            }
        }
    }
    if (!isV) {
#pragma unroll
        for (int ot = 0; ot < 4; ++ot) {
            const int og = o0 + wo + ot * 16 + quad * 4;     // 4 consecutive c (regs)
            const int h = (og >> 6) & 7;
            const int c0 = og & 63;
            unsigned short* dst = (og >= HIDDEN) ? Kb : Qb;
#pragma unroll
            for (int nt = 0; nt < 4; ++nt) {
                const int bn = bn0 + wn + nt * 16 + lo;
                const int b = bn >> 11, n = bn & 2047;
                uint2 u;
                u.x = pk2(acc[ot][nt][0], acc[ot][nt][1]);
                u.y = pk2(acc[ot][nt][2], acc[ot][nt][3]);
                *(uint2*)&dst[(((size_t)(b * HEADS + h)) * NN + n) * DH + c0] = u;
            }
        }
    } else {
#pragma unroll
        for (int mt = 0; mt < 4; ++mt) {
            const int bn = bn0 + wn + mt * 16 + quad * 4;    // 4 consecutive m (regs)
            const int b = bn >> 11, m = bn & 2047;
#pragma unroll
            for (int ot = 0; ot < 4; ++ot) {
                const int og = o0 + wo + ot * 16 + lo;
                const int h = (og >> 6) & 7;
                const int c = og & 63;
                uint2 u;
                u.x = pk2(acc[mt][ot][0], acc[mt][ot][1]);
                u.y = pk2(acc[mt][ot][2], acc[mt][ot][3]);
                *(uint2*)&Vb[(((size_t)(b * HEADS + h)) * DH + c) * NN + m] = u;
            }
        }
    }
}

// ---------------- Kernel B: MFMA flash attention (S^T form, swizzled LDS) ----------------
__global__ __launch_bounds__(256, 6) void flash_attn(const unsigned short* __restrict__ Qb,
                                                     const unsigned short* __restrict__ Kb,
                                                     const unsigned short* __restrict__ Vb,
                                                     unsigned short* __restrict__ Yb) {
    __shared__ unsigned short Ks[64 * 64], Vs[64 * 64], Ps[64 * 64];
    const int flat = blockIdx.x;
    const int rest = flat >> 3;
    const int bh = ((rest & 3) << 3) | (flat & 7);
    const int q0 = (rest >> 2) * 64;
    const int b = bh >> 3, h = bh & 7;
    const int t = threadIdx.x, l = t & 63, w = t >> 6, lo = l & 15, quad = l >> 4;
    const unsigned short* Qp = Qb + (size_t)bh * NN * DH;
    const unsigned short* Kp = Kb + (size_t)bh * NN * DH;
    const unsigned short* Vp = Vb + (size_t)bh * DH * NN;
    const int q = q0 + 16 * w + lo;
    const bf16x8 bQ0 = *(const bf16x8*)&Qp[(size_t)q * DH + quad * 8];
    const bf16x8 bQ1 = *(const bf16x8*)&Qp[(size_t)q * DH + 32 + quad * 8];
    f32x4 O[4];
#pragma unroll
    for (int i = 0; i < 4; ++i) O[i] = (f32x4){0.f, 0.f, 0.f, 0.f};
    float m_i = -INFINITY, l_i = 0.f;
    const int sr = t >> 3, sc = t & 7;
    const int kst0 = sr * 64 + SWZC(sr, sc);
    const int key = lo & 7;

    for (int m0 = 0; m0 < NN; m0 += 64) {
        __syncthreads();
        *(uint4*)&Ks[kst0]           = *(const uint4*)&Kp[(size_t)(m0 + sr) * DH + sc * 8];
        *(uint4*)&Ks[kst0 + 32 * 64] = *(const uint4*)&Kp[(size_t)(m0 + sr + 32) * DH + sc * 8];
        *(uint4*)&Vs[kst0]           = *(const uint4*)&Vp[(size_t)sr * NN + m0 + sc * 8];
        *(uint4*)&Vs[kst0 + 32 * 64] = *(const uint4*)&Vp[(size_t)(sr + 32) * NN + m0 + sc * 8];
        __syncthreads();
        f32x4 S[4];
#pragma unroll
        for (int nt = 0; nt < 4; ++nt) {
            const int rb = (nt * 16 + lo) * 64;
            bf16x8 a0 = *(const bf16x8*)&Ks[rb + SWZC(lo, quad)];
            bf16x8 a1 = *(const bf16x8*)&Ks[rb + SWZC(lo, quad + 4)];
            f32x4 z = (f32x4){0.f, 0.f, 0.f, 0.f};
            z = MFMA16(a0, bQ0, z);
            z = MFMA16(a1, bQ1, z);
            S[nt] = z;
        }
        float mx;
        {
            f32x4 mm;
#pragma unroll
            for (int i = 0; i < 4; ++i)
                mm[i] = fmaxf(fmaxf(S[0][i], S[1][i]), fmaxf(S[2][i], S[3][i]));
            mx = fmaxf(fmaxf(mm[0], mm[1]), fmaxf(mm[2], mm[3]));
        }
        mx = fmaxf(mx, __shfl_xor(mx, 16));
        mx = fmaxf(mx, __shfl_xor(mx, 32));
        const float mn = fmaxf(m_i, mx);
        const float alpha = EXP2(m_i - mn);
        m_i = mn;
        float ls = 0.f;
        const int prow = (16 * w + lo) * 64;
#pragma unroll
        for (int nt = 0; nt < 4; ++nt) {
            f32x4 p;
#pragma unroll
            for (int i = 0; i < 4; ++i) p[i] = EXP2(S[nt][i] - mn);
            ls += (p[0] + p[1]) + (p[2] + p[3]);
            uint2 u;
            u.x = pk2(p[0], p[1]);
            u.y = pk2(p[2], p[3]);
            *(uint2*)&Ps[prow + (((nt * 2 + (quad >> 1)) ^ key) << 3) + (quad & 1) * 4] = u;
        }
        ls += __shfl_xor(ls, 16);
        ls += __shfl_xor(ls, 32);
        l_i = l_i * alpha + ls;
        asm volatile("s_waitcnt lgkmcnt(0)" ::: "memory");
#pragma unroll
        for (int ct = 0; ct < 4; ++ct) O[ct] *= alpha;
        const bf16x8 pb0 = *(const bf16x8*)&Ps[prow + SWZC(lo, quad)];
        const bf16x8 pb1 = *(const bf16x8*)&Ps[prow + SWZC(lo, quad + 4)];
#pragma unroll
        for (int ct = 0; ct < 4; ++ct) {
            const int rb = (ct * 16 + lo) * 64;
            bf16x8 a0 = *(const bf16x8*)&Vs[rb + SWZC(lo, quad)];
            bf16x8 a1 = *(const bf16x8*)&Vs[rb + SWZC(lo, quad + 4)];
            O[ct] = MFMA16(a0, pb0, O[ct]);
            O[ct] = MFMA16(a1, pb1, O[ct]);
        }
    }
    const float inv = 1.f / l_i;
    unsigned short* yrow = Yb + (((size_t)(b * NN) + q)) * HIDDEN + h * DH;
#pragma unroll
    for (int ct = 0; ct < 4; ++ct) {
        uint2 u;
        u.x = pk2(O[ct][0] * inv, O[ct][1] * inv);
        u.y = pk2(O[ct][2] * inv, O[ct][3] * inv);
        *(uint2*)&yrow[ct * 16 + quad * 4] = u;
    }
}

// ---------------- Kernel C: out projection, 128x64 LDS-tiled MFMA GEMM + bias ----------------
// D[n][o]: A = Yb rows bn (k-contig), B = Wob rows o (k-contig). fp32 f32x4 stores over n.
__global__ __launch_bounds__(256, 4) void out_gemm(const unsigned short* __restrict__ Yb,
                                                   const unsigned short* __restrict__ Wob,
                                                   const float* __restrict__ bias,
                                                   float* __restrict__ out) {
    __shared__ unsigned short Ys[128 * 64], Wos[64 * 64];
    const int bn0 = blockIdx.x * 128, o0 = blockIdx.y * 64;
    const int t = threadIdx.x, l = t & 63, w = t >> 6, lo = l & 15, quad = l >> 4;
    const int wn = w * 32;                               // wave: 32 n-rows x 64 o-cols
    const int sr = t >> 1, scb = (t & 1) * 4;            // Ys staging
    const int sr2 = t >> 2, scb2 = (t & 3) * 2;          // Wos staging
    f32x4 acc[2][4];
#pragma unroll
    for (int i = 0; i < 2; ++i)
#pragma unroll
        for (int j = 0; j < 4; ++j) acc[i][j] = (f32x4){0.f, 0.f, 0.f, 0.f};

    for (int kc = 0; kc < HIDDEN; kc += 64) {
        __syncthreads();
#pragma unroll
        for (int j = 0; j < 4; ++j) {
            const int ch = scb + j;
            *(uint4*)&Ys[sr * 64 + SWZC(sr, ch)] =
                *(const uint4*)&Yb[(size_t)(bn0 + sr) * HIDDEN + kc + ch * 8];
        }
#pragma unroll
        for (int j = 0; j < 2; ++j) {
            const int ch = scb2 + j;
            *(uint4*)&Wos[sr2 * 64 + SWZC(sr2, ch)] =
                *(const uint4*)&Wob[(size_t)(o0 + sr2) * HIDDEN + kc + ch * 8];
        }
        __syncthreads();
#pragma unroll
        for (int kk = 0; kk < 2; ++kk) {
            const int swz = SWZC(lo, kk * 4 + quad);
            bf16x8 bv[4];
#pragma unroll
            for (int ot = 0; ot < 4; ++ot) bv[ot] = *(const bf16x8*)&Wos[(ot * 16 + lo) * 64 + swz];
#pragma unroll
            for (int mt = 0; mt < 2; ++mt) {
                bf16x8 av = *(const bf16x8*)&Ys[(wn + mt * 16 + lo) * 64 + swz];
#pragma unroll
                for (int ot = 0; ot < 4; ++ot) acc[mt][ot] = MFMA16(av, bv[ot], acc[mt][ot]);
            }
        }
    }
#pragma unroll
    for (int mt = 0; mt < 2; ++mt) {
        const int bn = bn0 + wn + mt * 16 + quad * 4;    // 4 consecutive n (regs)
        const int b = bn >> 11, n = bn & 2047;
#pragma unroll
        for (int ot = 0; ot < 4; ++ot) {
            const int o = o0 + ot * 16 + lo;
            *(f32x4*)&out[((size_t)(b * CDIM + o)) * NN + n] = acc[mt][ot] + bias[o];
        }
    }
}

extern "C" void kernel_launch(void* const* d_in, const int* in_sizes, int n_in,
                              void* d_out, int out_size, void* d_ws, size_t ws_size,
                              hipStream_t stream) {
    const float* x     = (const float*)d_in[0];
    const float* w_qkv = (const float*)d_in[1];
    const float* w_out = (const float*)d_in[2];
    const float* b_out = (const float*)d_in[3];
    float* out = (float*)d_out;

    unsigned short* Wqb = (unsigned short*)d_ws;                  // 1536*256
    unsigned short* Wob = Wqb + (size_t)THREEH * CDIM;            // 256*512
    unsigned short* Xt  = Wob + (size_t)CDIM * HIDDEN;            // [b][n][c] bf16
    unsigned short* Qb  = Xt + (size_t)BB * NN * CDIM;            // [b][h][n][c] pre-scaled
    unsigned short* Kb  = Qb + (size_t)BB * HEADS * NN * DH;      // [b][h][n][c]
    unsigned short* Vb  = Kb + (size_t)BB * HEADS * NN * DH;      // [b][h][c][n]
    unsigned short* Yb  = Vb + (size_t)BB * HEADS * DH * NN;      // [b][n][hidden]

    prep_w<<<512, 256, 0, stream>>>(w_qkv, w_out, (unsigned*)Wqb, (unsigned*)Wob);
    prep_x<<<dim3(NN / 64, CDIM / 64, BB), 256, 0, stream>>>(x, Xt);
    qkv_gemm<<<dim3(BB * NN / 128, THREEH / 128), 256, 0, stream>>>(Xt, Wqb, Qb, Kb, Vb);
    flash_attn<<<1024, 256, 0, stream>>>(Qb, Kb, Vb, Yb);
    out_gemm<<<dim3(BB * NN / 128, CDIM / 64), 256, 0, stream>>>(Yb, Wob, b_out, out);
}